// Round 4
// baseline (1495.290 us; speedup 1.0000x reference)
//
#include <hip/hip_runtime.h>

#define D 128
#define HD 128
#define DE 16
#define MSG_IN 273
#define EB 64        // edges per block (mfma path)
#define NT 256
#define KP1 288      // padded msg K = 9 chunks of 32
#define NCH1 9
#define NCH2 4
#define NB 32
#define MSG_PAD 276  // fp32 fallback kernel
#define HID_PAD 132

typedef __attribute__((ext_vector_type(8))) short short8v;
typedef __attribute__((ext_vector_type(4))) float f32x4;
typedef unsigned short ushort_t;

__device__ __forceinline__ unsigned short f2bf(float v) {
    unsigned int u = __builtin_bit_cast(unsigned int, v);
    u += 0x7fffu + ((u >> 16) & 1u);
    return (unsigned short)(u >> 16);
}

// ---------------- weight repack: fp32 [K][N] -> bf16 transposed [N][Kpad] ----------------
__global__ void repack_kernel(const float* __restrict__ Wm1, const float* __restrict__ Wm2,
                              ushort_t* __restrict__ W1p, ushort_t* __restrict__ W2p) {
    int idx = blockIdx.x * 256 + threadIdx.x;
    const int n1 = 128 * KP1;
    if (idx < n1) {
        int n = idx / KP1, k = idx % KP1;
        float v = (k < MSG_IN) ? Wm1[(size_t)k * HD + n] : 0.f;
        W1p[idx] = f2bf(v);
    } else {
        int i2 = idx - n1;
        if (i2 < HD * D) {
            int n = i2 / HD, k = i2 % HD;
            W2p[i2] = f2bf(Wm2[(size_t)k * D + n]);
        }
    }
}

// ---------------- counting sort by dst ----------------
__global__ void hist_kernel(const int* __restrict__ dst, int* __restrict__ cnt, int E) {
    int i = blockIdx.x * 256 + threadIdx.x;
    if (i < E) atomicAdd(&cnt[dst[i]], 1);
}

// single wave (64 threads, 1 block): exclusive scan of cnt -> cursor
__global__ void scan_kernel(const int* __restrict__ cnt, int* __restrict__ cursor, int Nn) {
    const int l = threadIdx.x;   // 0..63
    int running = 0;
    for (int base = 0; base < Nn; base += 64) {
        int i = base + l;
        int v = (i < Nn) ? cnt[i] : 0;
        int s = v;
        #pragma unroll
        for (int off = 1; off < 64; off <<= 1) {
            int u = __shfl_up(s, off, 64);
            if (l >= off) s += u;
        }
        if (i < Nn) cursor[i] = running + s - v;   // exclusive
        running += __shfl(s, 63, 64);
    }
}

__global__ void scatter_kernel(const int* __restrict__ dst, int* cursor,
                               int* __restrict__ perm, int* __restrict__ sdst, int E) {
    int i = blockIdx.x * 256 + threadIdx.x;
    if (i < E) {
        int d = dst[i];
        int s = atomicAdd(&cursor[d], 1);
        perm[s] = i;
        sdst[s] = d;
    }
}

// ---------------- edge kernel (MFMA bf16, CSR-sorted): msg MLP + LDS segment reduce ----------------
__global__ __launch_bounds__(NT, 4) void edge_mfma_csr_kernel(
    const float* __restrict__ f, const float* __restrict__ x,
    const float* __restrict__ w, const int* __restrict__ src,
    const int* __restrict__ perm, const int* __restrict__ sdst,
    const ushort_t* __restrict__ W1p, const float* __restrict__ bm1,
    const ushort_t* __restrict__ W2p, const float* __restrict__ bm2,
    float* msum, int E)
{
    // [chunk][edge][32 k] bf16; after B1, aliased as float acc[64][128] (32 KB)
    __shared__ __align__(16) ushort_t msg_c[NCH1 * EB * 32];   // 36,864 B
    __shared__ int s_rowdst[EB];
    __shared__ unsigned char s_rid[EB];
    __shared__ int s_nd;

    const int t    = threadIdx.x;
    const int lane = t & 63;
    const int wv   = t >> 6;              // wave owns sorted slots [16wv, 16wv+16)
    const int e0   = blockIdx.x * EB;

    // ---- wave 0: block meta (row ids = distinct-dst index per slot) ----
    if (wv == 0) {
        const int slot = e0 + lane;
        const int d    = (slot < E) ? sdst[slot] : -1;
        const int dup  = __shfl_up(d, 1, 64);
        const int trans = (lane == 0) ? 1 : (d != dup ? 1 : 0);
        unsigned long long bal = __ballot(trans != 0);
        unsigned long long mask_le = (lane == 63) ? ~0ull : ((1ull << (lane + 1)) - 1ull);
        int rid = (int)__popcll(bal & mask_le) - 1;
        s_rid[lane] = (unsigned char)rid;
        if (trans) s_rowdst[rid] = d;
        if (lane == 63) s_nd = rid + 1;
    }

    // ---- wave-local staging: 4 lanes per sorted slot ----
    {
        const int el   = lane >> 2;       // 0..15 slot within wave
        const int q    = lane & 3;
        const int sl   = wv * 16 + el;
        const int slot = e0 + sl;
        const bool ok  = slot < E;
        const int ge   = ok ? perm[slot] : 0;
        const int ns   = ok ? src[ge] : 0;
        const int ndn  = ok ? sdst[slot] : 0;

        // chunks 0..7: f[src] (k 0..127) | f[dst] (k 128..255)
        #pragma unroll
        for (int i = 0; i < 8; ++i) {
            const int k0 = i * 32 + q * 8;
            union { unsigned short us[8]; short8v v; } pk;
            if (ok) {
                const float* base = (k0 < D) ? (f + (size_t)ns * D + k0)
                                             : (f + (size_t)ndn * D + (k0 - D));
                float4 v0 = *(const float4*)base;
                float4 v1 = *(const float4*)(base + 4);
                pk.us[0] = f2bf(v0.x); pk.us[1] = f2bf(v0.y);
                pk.us[2] = f2bf(v0.z); pk.us[3] = f2bf(v0.w);
                pk.us[4] = f2bf(v1.x); pk.us[5] = f2bf(v1.y);
                pk.us[6] = f2bf(v1.z); pk.us[7] = f2bf(v1.w);
            } else {
                #pragma unroll
                for (int j = 0; j < 8; ++j) pk.us[j] = 0;
            }
            *(short8v*)&msg_c[(i * EB + sl) * 32 + q * 8] = pk.v;
        }
        // chunk 8: q=0 -> w[0..8); q=1 -> w[8..16); q=2 -> sqd; q=3 -> zeros
        {
            union { unsigned short us[8]; short8v v; } pk;
            #pragma unroll
            for (int j = 0; j < 8; ++j) pk.us[j] = 0;
            if (ok) {
                if (q < 2) {
                    float4 w0 = *(const float4*)(w + (size_t)ge * DE + q * 8);
                    float4 w1 = *(const float4*)(w + (size_t)ge * DE + q * 8 + 4);
                    pk.us[0] = f2bf(w0.x); pk.us[1] = f2bf(w0.y);
                    pk.us[2] = f2bf(w0.z); pk.us[3] = f2bf(w0.w);
                    pk.us[4] = f2bf(w1.x); pk.us[5] = f2bf(w1.y);
                    pk.us[6] = f2bf(w1.z); pk.us[7] = f2bf(w1.w);
                } else if (q == 2) {
                    float dx = x[ns*3+0] - x[ndn*3+0];
                    float dy = x[ns*3+1] - x[ndn*3+1];
                    float dz = x[ns*3+2] - x[ndn*3+2];
                    pk.us[0] = f2bf(dx*dx + dy*dy + dz*dz);
                }
            }
            *(short8v*)&msg_c[(8 * EB + sl) * 32 + q * 8] = pk.v;
        }
    }
    // no barrier: msg/hid rows are wave-private; lgkmcnt orders RAW within wave.

    const int col  = lane & 15;     // output col within 16-tile / A row
    const int g    = lane >> 4;     // k-group
    const int erow = wv * 16 + col;

    // ---- layer 1: [16,288] x [288,128] per wave ----
    f32x4 acc[8];
    #pragma unroll
    for (int ct = 0; ct < 8; ++ct) {
        float bv = bm1[ct * 16 + col];
        acc[ct] = (f32x4){bv, bv, bv, bv};
    }
    for (int c = 0; c < NCH1; ++c) {
        short8v a = *(const short8v*)&msg_c[(c * EB + erow) * 32 + g * 8];
        #pragma unroll
        for (int ct = 0; ct < 8; ++ct) {
            short8v b = *(const short8v*)&W1p[(size_t)(ct * 16 + col) * KP1 + c * 32 + g * 8];
            acc[ct] = __builtin_amdgcn_mfma_f32_16x16x32_bf16(a, b, acc[ct], 0, 0, 0);
        }
    }
    // relu -> bf16 hid, aliased into msg_c chunks 0..3 (wave-private rows)
    #pragma unroll
    for (int ct = 0; ct < 8; ++ct) {
        const int h  = ct * 16 + col;
        const int hc = h >> 5, hi = h & 31;
        #pragma unroll
        for (int r = 0; r < 4; ++r) {
            const int e = wv * 16 + g * 4 + r;
            msg_c[(hc * EB + e) * 32 + hi] = f2bf(fmaxf(acc[ct][r], 0.f));
        }
    }

    // ---- layer 2: [16,128] x [128,128] per wave ----
    f32x4 acc2[8];
    #pragma unroll
    for (int ct = 0; ct < 8; ++ct) {
        float bv = bm2[ct * 16 + col];
        acc2[ct] = (f32x4){bv, bv, bv, bv};
    }
    for (int c = 0; c < NCH2; ++c) {
        short8v a = *(const short8v*)&msg_c[(c * EB + erow) * 32 + g * 8];
        #pragma unroll
        for (int ct = 0; ct < 8; ++ct) {
            short8v b = *(const short8v*)&W2p[(size_t)(ct * 16 + col) * HD + c * 32 + g * 8];
            acc2[ct] = __builtin_amdgcn_mfma_f32_16x16x32_bf16(a, b, acc2[ct], 0, 0, 0);
        }
    }

    // ---- B1: everyone done reading msg_c; alias it as fp32 accumulator ----
    __syncthreads();
    float* accf = (float*)msg_c;          // acc[64][128] fp32 = 32 KB
    {
        float4 z = {0.f, 0.f, 0.f, 0.f};
        #pragma unroll
        for (int i = 0; i < 8; ++i)
            *(float4*)&accf[(i * NT + t) * 4] = z;
    }
    __syncthreads();                      // B2

    // ---- LDS segment reduce: ds_add per fragment into row rid[slot] ----
    #pragma unroll
    for (int r = 0; r < 4; ++r) {
        const int sl = wv * 16 + g * 4 + r;
        if (e0 + sl < E) {
            const int rid = s_rid[sl];
            float* ap = accf + rid * 128 + col;
            #pragma unroll
            for (int ct = 0; ct < 8; ++ct)
                atomicAdd(ap + ct * 16, acc2[ct][r]);
        }
    }
    __syncthreads();                      // B3

    // ---- writeout: plain stores for interior dsts, atomics for boundary ----
    const int ndist = s_nd;
    const int prevd = (e0 > 0) ? sdst[e0 - 1] : -3;
    const int nxtd  = (e0 + EB < E) ? sdst[e0 + EB] : -3;
    for (int dr = t >> 5; dr < ndist; dr += 8) {
        const int dg = s_rowdst[dr];
        if (dg < 0) continue;             // tail padding rows
        const bool bnd = (dr == 0 && prevd == dg) || (dr == ndist - 1 && nxtd == dg);
        const int c4 = (t & 31) * 4;
        float4 v = *(float4*)&accf[dr * 128 + c4];
        float* p = msum + (size_t)dg * D + c4;
        if (bnd) {
            atomicAdd(p, v.x); atomicAdd(p + 1, v.y);
            atomicAdd(p + 2, v.z); atomicAdd(p + 3, v.w);
        } else {
            *(float4*)p = v;
        }
    }
}

// ---------------- edge kernel (MFMA bf16, atomic fallback) ----------------
__global__ __launch_bounds__(NT, 4) void edge_mfma_kernel(
    const float* __restrict__ f, const float* __restrict__ x,
    const float* __restrict__ w, const int* __restrict__ src,
    const int* __restrict__ dst,
    const ushort_t* __restrict__ W1p, const float* __restrict__ bm1,
    const ushort_t* __restrict__ W2p, const float* __restrict__ bm2,
    float* msum, int E)
{
    __shared__ __align__(16) ushort_t msg_c[NCH1 * EB * 32];

    const int t    = threadIdx.x;
    const int lane = t & 63;
    const int wv   = t >> 6;
    const int e0   = blockIdx.x * EB;

    {
        const int el = lane >> 2;
        const int q  = lane & 3;
        const int ge = e0 + wv * 16 + el;
        const bool ok = ge < E;
        const int ns = ok ? src[ge] : 0;
        const int nd = ok ? dst[ge] : 0;
        const int mrow = wv * 16 + el;

        #pragma unroll
        for (int i = 0; i < 8; ++i) {
            const int k0 = i * 32 + q * 8;
            union { unsigned short us[8]; short8v v; } pk;
            if (ok) {
                const float* base = (k0 < D) ? (f + (size_t)ns * D + k0)
                                             : (f + (size_t)nd * D + (k0 - D));
                float4 v0 = *(const float4*)base;
                float4 v1 = *(const float4*)(base + 4);
                pk.us[0] = f2bf(v0.x); pk.us[1] = f2bf(v0.y);
                pk.us[2] = f2bf(v0.z); pk.us[3] = f2bf(v0.w);
                pk.us[4] = f2bf(v1.x); pk.us[5] = f2bf(v1.y);
                pk.us[6] = f2bf(v1.z); pk.us[7] = f2bf(v1.w);
            } else {
                #pragma unroll
                for (int j = 0; j < 8; ++j) pk.us[j] = 0;
            }
            *(short8v*)&msg_c[(i * EB + mrow) * 32 + q * 8] = pk.v;
        }
        {
            union { unsigned short us[8]; short8v v; } pk;
            #pragma unroll
            for (int j = 0; j < 8; ++j) pk.us[j] = 0;
            if (ok) {
                if (q < 2) {
                    float4 w0 = *(const float4*)(w + (size_t)ge * DE + q * 8);
                    float4 w1 = *(const float4*)(w + (size_t)ge * DE + q * 8 + 4);
                    pk.us[0] = f2bf(w0.x); pk.us[1] = f2bf(w0.y);
                    pk.us[2] = f2bf(w0.z); pk.us[3] = f2bf(w0.w);
                    pk.us[4] = f2bf(w1.x); pk.us[5] = f2bf(w1.y);
                    pk.us[6] = f2bf(w1.z); pk.us[7] = f2bf(w1.w);
                } else if (q == 2) {
                    float dx = x[ns*3+0] - x[nd*3+0];
                    float dy = x[ns*3+1] - x[nd*3+1];
                    float dz = x[ns*3+2] - x[nd*3+2];
                    pk.us[0] = f2bf(dx*dx + dy*dy + dz*dz);
                }
            }
            *(short8v*)&msg_c[(8 * EB + mrow) * 32 + q * 8] = pk.v;
        }
    }

    const int col  = lane & 15;
    const int g    = lane >> 4;
    const int erow = wv * 16 + col;

    f32x4 acc[8];
    #pragma unroll
    for (int ct = 0; ct < 8; ++ct) {
        float bv = bm1[ct * 16 + col];
        acc[ct] = (f32x4){bv, bv, bv, bv};
    }
    for (int c = 0; c < NCH1; ++c) {
        short8v a = *(const short8v*)&msg_c[(c * EB + erow) * 32 + g * 8];
        #pragma unroll
        for (int ct = 0; ct < 8; ++ct) {
            short8v b = *(const short8v*)&W1p[(size_t)(ct * 16 + col) * KP1 + c * 32 + g * 8];
            acc[ct] = __builtin_amdgcn_mfma_f32_16x16x32_bf16(a, b, acc[ct], 0, 0, 0);
        }
    }
    #pragma unroll
    for (int ct = 0; ct < 8; ++ct) {
        const int h  = ct * 16 + col;
        const int hc = h >> 5, hi = h & 31;
        #pragma unroll
        for (int r = 0; r < 4; ++r) {
            const int e = wv * 16 + g * 4 + r;
            msg_c[(hc * EB + e) * 32 + hi] = f2bf(fmaxf(acc[ct][r], 0.f));
        }
    }

    f32x4 acc2[8];
    #pragma unroll
    for (int ct = 0; ct < 8; ++ct) {
        float bv = bm2[ct * 16 + col];
        acc2[ct] = (f32x4){bv, bv, bv, bv};
    }
    for (int c = 0; c < NCH2; ++c) {
        short8v a = *(const short8v*)&msg_c[(c * EB + erow) * 32 + g * 8];
        #pragma unroll
        for (int ct = 0; ct < 8; ++ct) {
            short8v b = *(const short8v*)&W2p[(size_t)(ct * 16 + col) * HD + c * 32 + g * 8];
            acc2[ct] = __builtin_amdgcn_mfma_f32_16x16x32_bf16(a, b, acc2[ct], 0, 0, 0);
        }
    }

    #pragma unroll
    for (int r = 0; r < 4; ++r) {
        const int el = wv * 16 + g * 4 + r;
        const int ge = e0 + el;
        if (ge < E) {
            const int dg = dst[ge];
            float* p = msum + (size_t)dg * D + col;
            #pragma unroll
            for (int ct = 0; ct < 8; ++ct)
                atomicAdd(p + ct * 16, acc2[ct][r]);
        }
    }
}

// ---------------- fp32 fallback edge kernel (only if ws too small to repack) ----------------
__global__ __launch_bounds__(NT, 2) void edge_kernel_f32(
    const float* __restrict__ f, const float* __restrict__ x,
    const float* __restrict__ w, const int* __restrict__ src,
    const int* __restrict__ dst,
    const float* __restrict__ Wm1, const float* __restrict__ bm1,
    const float* __restrict__ Wm2, const float* __restrict__ bm2,
    float* msum, int E)
{
    __shared__ __align__(16) float msg[32][MSG_PAD];
    __shared__ __align__(16) float hid[32][HID_PAD];
    __shared__ int s_src[32], s_dst[32];

    const int t  = threadIdx.x;
    const int e0 = blockIdx.x * 32;
    const int ne = min(32, E - e0);

    if (t < ne) { s_src[t] = src[e0 + t]; s_dst[t] = dst[e0 + t]; }
    __syncthreads();
    {
        const int half = t >> 7, tt = t & 127;
        for (int e = 0; e < ne; ++e) {
            int node = half ? s_dst[e] : s_src[e];
            msg[e][half * D + tt] = f[(size_t)node * D + tt];
        }
    }
    for (int idx = t; idx < 32 * DE; idx += NT) {
        int e = idx >> 4, k = idx & 15;
        if (e < ne) msg[e][2 * D + k] = w[(size_t)(e0 + e) * DE + k];
    }
    if (t < ne) {
        int s = s_src[t], dd = s_dst[t];
        float dx = x[s*3+0]-x[dd*3+0], dy = x[s*3+1]-x[dd*3+1], dz = x[s*3+2]-x[dd*3+2];
        msg[t][2*D + DE] = dx*dx + dy*dy + dz*dz;
    }
    __syncthreads();

    const int tc = t & 15, te2 = (t >> 4) * 2, c0 = tc * 8;
    float a1[2][8];
    #pragma unroll
    for (int c = 0; c < 8; ++c) { float bv = bm1[c0 + c]; a1[0][c] = bv; a1[1][c] = bv; }
    for (int i = 0; i < 272; i += 4) {
        float m0[4], m1[4];
        *(float4*)m0 = *(const float4*)&msg[te2][i];
        *(float4*)m1 = *(const float4*)&msg[te2 + 1][i];
        #pragma unroll
        for (int r = 0; r < 4; ++r) {
            float wr[8];
            *(float4*)&wr[0] = *(const float4*)(Wm1 + (size_t)(i + r) * HD + c0);
            *(float4*)&wr[4] = *(const float4*)(Wm1 + (size_t)(i + r) * HD + c0 + 4);
            #pragma unroll
            for (int c = 0; c < 8; ++c) { a1[0][c] += m0[r]*wr[c]; a1[1][c] += m1[r]*wr[c]; }
        }
    }
    {
        float m0 = msg[te2][272], m1 = msg[te2 + 1][272];
        float wr[8];
        *(float4*)&wr[0] = *(const float4*)(Wm1 + (size_t)272 * HD + c0);
        *(float4*)&wr[4] = *(const float4*)(Wm1 + (size_t)272 * HD + c0 + 4);
        #pragma unroll
        for (int c = 0; c < 8; ++c) { a1[0][c] += m0*wr[c]; a1[1][c] += m1*wr[c]; }
    }
    #pragma unroll
    for (int j = 0; j < 2; ++j) {
        float v[8];
        #pragma unroll
        for (int c = 0; c < 8; ++c) v[c] = fmaxf(a1[j][c], 0.f);
        *(float4*)&hid[te2 + j][c0] = *(float4*)&v[0];
        *(float4*)&hid[te2 + j][c0 + 4] = *(float4*)&v[4];
    }
    __syncthreads();
    float a2[2][8];
    #pragma unroll
    for (int c = 0; c < 8; ++c) { float bv = bm2[c0 + c]; a2[0][c] = bv; a2[1][c] = bv; }
    for (int h = 0; h < HD; h += 4) {
        float m0[4], m1[4];
        *(float4*)m0 = *(const float4*)&hid[te2][h];
        *(float4*)m1 = *(const float4*)&hid[te2 + 1][h];
        #pragma unroll
        for (int r = 0; r < 4; ++r) {
            float wr[8];
            *(float4*)&wr[0] = *(const float4*)(Wm2 + (size_t)(h + r) * D + c0);
            *(float4*)&wr[4] = *(const float4*)(Wm2 + (size_t)(h + r) * D + c0 + 4);
            #pragma unroll
            for (int c = 0; c < 8; ++c) { a2[0][c] += m0[r]*wr[c]; a2[1][c] += m1[r]*wr[c]; }
        }
    }
    #pragma unroll
    for (int j = 0; j < 2; ++j) {
        int e = te2 + j;
        if (e < ne) {
            float* p = msum + (size_t)s_dst[e] * D + c0;
            #pragma unroll
            for (int c = 0; c < 8; ++c) atomicAdd(p + c, a2[j][c]);
        }
    }
}

// ---------------- node kernel: update MLP (fp32) ----------------
__global__ __launch_bounds__(NT, 2) void node_kernel(
    const float* __restrict__ f, const float* msum,
    const float* __restrict__ Wu1, const float* __restrict__ bu1,
    const float* __restrict__ Wu2, const float* __restrict__ bu2,
    float* out, int Nn)
{
    __shared__ __align__(16) float hin[NB][HID_PAD];
    __shared__ __align__(16) float hid[NB][HID_PAD];
    const int t  = threadIdx.x;
    const int n0 = blockIdx.x * NB;
    const int nn = min(NB, Nn - n0);

    {
        const int half = t >> 7, tt = t & 127;
        for (int e = half; e < nn; e += 2) {
            size_t off = (size_t)(n0 + e) * D + tt;
            hin[e][tt] = msum[off] + f[off];
        }
    }
    __syncthreads();

    const int tc = t & 15, te2 = (t >> 4) * 2, c0 = tc * 8;
    float a1[2][8];
    #pragma unroll
    for (int c = 0; c < 8; ++c) { float bv = bu1[c0 + c]; a1[0][c] = bv; a1[1][c] = bv; }
    for (int i = 0; i < D; i += 4) {
        float m0[4], m1[4];
        *(float4*)m0 = *(const float4*)&hin[te2][i];
        *(float4*)m1 = *(const float4*)&hin[te2 + 1][i];
        #pragma unroll
        for (int r = 0; r < 4; ++r) {
            float wr[8];
            *(float4*)&wr[0] = *(const float4*)(Wu1 + (size_t)(i + r) * HD + c0);
            *(float4*)&wr[4] = *(const float4*)(Wu1 + (size_t)(i + r) * HD + c0 + 4);
            #pragma unroll
            for (int c = 0; c < 8; ++c) { a1[0][c] += m0[r]*wr[c]; a1[1][c] += m1[r]*wr[c]; }
        }
    }
    #pragma unroll
    for (int j = 0; j < 2; ++j) {
        float v[8];
        #pragma unroll
        for (int c = 0; c < 8; ++c) v[c] = fmaxf(a1[j][c], 0.f);
        *(float4*)&hid[te2 + j][c0] = *(float4*)&v[0];
        *(float4*)&hid[te2 + j][c0 + 4] = *(float4*)&v[4];
    }
    __syncthreads();
    float a2[2][8];
    #pragma unroll
    for (int c = 0; c < 8; ++c) { float bv = bu2[c0 + c]; a2[0][c] = bv; a2[1][c] = bv; }
    for (int h = 0; h < HD; h += 4) {
        float m0[4], m1[4];
        *(float4*)m0 = *(const float4*)&hid[te2][h];
        *(float4*)m1 = *(const float4*)&hid[te2 + 1][h];
        #pragma unroll
        for (int r = 0; r < 4; ++r) {
            float wr[8];
            *(float4*)&wr[0] = *(const float4*)(Wu2 + (size_t)(h + r) * D + c0);
            *(float4*)&wr[4] = *(const float4*)(Wu2 + (size_t)(h + r) * D + c0 + 4);
            #pragma unroll
            for (int c = 0; c < 8; ++c) { a2[0][c] += m0[r]*wr[c]; a2[1][c] += m1[r]*wr[c]; }
        }
    }
    #pragma unroll
    for (int j = 0; j < 2; ++j) {
        int e = te2 + j, gn = n0 + e;
        if (e < nn) {
            *(float4*)(out + (size_t)gn * D + c0) = *(float4*)&a2[j][0];
            *(float4*)(out + (size_t)gn * D + c0 + 4) = *(float4*)&a2[j][4];
        }
    }
}

extern "C" void kernel_launch(void* const* d_in, const int* in_sizes, int n_in,
                              void* d_out, int out_size, void* d_ws, size_t ws_size,
                              hipStream_t stream) {
    const float* f   = (const float*)d_in[0];
    const float* x   = (const float*)d_in[1];
    const float* w   = (const float*)d_in[2];
    const int*   src = (const int*)d_in[3];
    const int*   dst = (const int*)d_in[4];
    const float* Wm1 = (const float*)d_in[5];
    const float* bm1 = (const float*)d_in[6];
    const float* Wm2 = (const float*)d_in[7];
    const float* bm2 = (const float*)d_in[8];
    const float* Wu1 = (const float*)d_in[9];
    const float* bu1 = (const float*)d_in[10];
    const float* Wu2 = (const float*)d_in[11];
    const float* bu2 = (const float*)d_in[12];

    const int Nn = in_sizes[0] / D;
    const int E  = in_sizes[3];

    const size_t msum_bytes = (size_t)Nn * D * sizeof(float);
    const size_t wbytes = (size_t)(128 * KP1 + HD * D) * sizeof(ushort_t); // 106,496 B

    auto align512 = [](size_t v) { return (v + 511) & ~(size_t)511; };

    // CSR layout in workspace
    size_t off = 0;
    const size_t o_w    = off; off = align512(off + wbytes);
    const size_t o_cnt  = off; off = align512(off + (size_t)Nn * 4);
    const size_t o_cur  = off; off = align512(off + (size_t)Nn * 4);
    const size_t o_perm = off; off = align512(off + (size_t)E * 4);
    const size_t o_sdst = off; off = align512(off + (size_t)E * 4);
    const size_t o_msum = off; off = align512(off + msum_bytes);
    const size_t csr_total = off;

    char* wsb = (char*)d_ws;

    if (ws_size >= csr_total) {
        // ---------------- CSR path ----------------
        ushort_t* W1p  = (ushort_t*)(wsb + o_w);
        ushort_t* W2p  = W1p + 128 * KP1;
        int* cnt       = (int*)(wsb + o_cnt);
        int* cursor    = (int*)(wsb + o_cur);
        int* perm      = (int*)(wsb + o_perm);
        int* sdst      = (int*)(wsb + o_sdst);
        float* msum    = (float*)(wsb + o_msum);

        hipMemsetAsync(cnt, 0, (size_t)Nn * 4, stream);
        hipMemsetAsync(msum, 0, msum_bytes, stream);

        const int rp_elems = 128 * KP1 + HD * D;
        repack_kernel<<<dim3((rp_elems + 255) / 256), dim3(256), 0, stream>>>(Wm1, Wm2, W1p, W2p);
        hist_kernel<<<dim3((E + 255) / 256), dim3(256), 0, stream>>>(dst, cnt, E);
        scan_kernel<<<dim3(1), dim3(64), 0, stream>>>(cnt, cursor, Nn);
        scatter_kernel<<<dim3((E + 255) / 256), dim3(256), 0, stream>>>(dst, cursor, perm, sdst, E);
        edge_mfma_csr_kernel<<<dim3((E + EB - 1) / EB), dim3(NT), 0, stream>>>(
            f, x, w, src, perm, sdst, W1p, bm1, W2p, bm2, msum, E);
        node_kernel<<<dim3((Nn + NB - 1) / NB), dim3(NT), 0, stream>>>(
            f, msum, Wu1, bu1, Wu2, bu2, (float*)d_out, Nn);
        return;
    }

    // ---------------- fallback paths ----------------
    const size_t woff = align512(wbytes);
    float* msum;
    ushort_t* W1p = nullptr;
    bool use_mfma;
    if (ws_size >= woff + msum_bytes) {
        W1p = (ushort_t*)d_ws;
        msum = (float*)(wsb + woff);
        use_mfma = true;
    } else if (ws_size >= wbytes) {
        W1p = (ushort_t*)d_ws;
        msum = (float*)d_out;
        use_mfma = true;
    } else {
        use_mfma = false;
        msum = (ws_size >= msum_bytes) ? (float*)d_ws : (float*)d_out;
    }

    hipMemsetAsync(msum, 0, msum_bytes, stream);

    if (use_mfma) {
        ushort_t* W2p = W1p + 128 * KP1;
        const int rp_elems = 128 * KP1 + HD * D;
        repack_kernel<<<dim3((rp_elems + 255) / 256), dim3(256), 0, stream>>>(Wm1, Wm2, W1p, W2p);
        edge_mfma_kernel<<<dim3((E + EB - 1) / EB), dim3(NT), 0, stream>>>(
            f, x, w, src, dst, W1p, bm1, W2p, bm2, msum, E);
    } else {
        edge_kernel_f32<<<dim3((E + 31) / 32), dim3(NT), 0, stream>>>(
            f, x, w, src, dst, Wm1, bm1, Wm2, bm2, msum, E);
    }
    node_kernel<<<dim3((Nn + NB - 1) / NB), dim3(NT), 0, stream>>>(
        f, msum, Wu1, bu1, Wu2, bu2, (float*)d_out, Nn);
}

// Round 5
// 539.015 us; speedup vs baseline: 2.7741x; 2.7741x over previous
//
#include <hip/hip_runtime.h>

#define D 128
#define HD 128
#define DE 16
#define MSG_IN 273
#define EB 64        // edges per block (mfma path)
#define NT 256
#define KP1 288      // padded msg K = 9 chunks of 32
#define NCH1 9
#define NCH2 4
#define NB 32
#define MSG_PAD 276  // fp32 fallback kernel
#define HID_PAD 132

typedef __attribute__((ext_vector_type(8))) short short8v;
typedef __attribute__((ext_vector_type(4))) float f32x4;
typedef unsigned short ushort_t;

__device__ __forceinline__ unsigned short f2bf(float v) {
    unsigned int u = __builtin_bit_cast(unsigned int, v);
    u += 0x7fffu + ((u >> 16) & 1u);
    return (unsigned short)(u >> 16);
}
__device__ __forceinline__ float bf2f(ushort_t u) {
    return __builtin_bit_cast(float, (unsigned int)u << 16);
}

// ---------------- weight repack: fp32 [K][N] -> bf16 transposed [N][Kpad] ----------------
__global__ void repack_kernel(const float* __restrict__ Wm1, const float* __restrict__ Wm2,
                              ushort_t* __restrict__ W1p, ushort_t* __restrict__ W2p) {
    int idx = blockIdx.x * 256 + threadIdx.x;
    const int n1 = 128 * KP1;
    if (idx < n1) {
        int n = idx / KP1, k = idx % KP1;
        float v = (k < MSG_IN) ? Wm1[(size_t)k * HD + n] : 0.f;
        W1p[idx] = f2bf(v);
    } else {
        int i2 = idx - n1;
        if (i2 < HD * D) {
            int n = i2 / HD, k = i2 % HD;
            W2p[i2] = f2bf(Wm2[(size_t)k * D + n]);
        }
    }
}

// ---------------- edge kernel v5: 4x2 tile/wave, pk-bf16 atomic scatter ----------------
// Wave wv computes ALL 64 edges x output cols [wv*32, wv*32+32).
// B-frags reused across 4 row-tiles (MFMA:VMEM 4:1), next-chunk prefetch.
__global__ __launch_bounds__(NT, 4) void edge_mfma_kernel(
    const float* __restrict__ f, const float* __restrict__ x,
    const float* __restrict__ w, const int* __restrict__ src,
    const int* __restrict__ dst,
    const ushort_t* __restrict__ W1p, const float* __restrict__ bm1,
    const ushort_t* __restrict__ W2p, const float* __restrict__ bm2,
    ushort_t* msum, int E)
{
    // [chunk][edge][32 k] bf16; hid aliases chunks 0..3 after B1. 36,864 B.
    __shared__ __align__(16) ushort_t msg_c[NCH1 * EB * 32];
    __shared__ int s_dst[EB];

    const int t    = threadIdx.x;
    const int lane = t & 63;
    const int wv   = t >> 6;
    const int e0   = blockIdx.x * EB;

    if (t < EB) s_dst[t] = (e0 + t < E) ? dst[e0 + t] : 0;

    // ---- wave-local staging: 4 lanes per edge (wave stages edges [16wv,16wv+16)) ----
    {
        const int el = lane >> 2;
        const int q  = lane & 3;
        const int ge = e0 + wv * 16 + el;
        const bool ok = ge < E;
        const int ns = ok ? src[ge] : 0;
        const int nd = ok ? dst[ge] : 0;
        const int mrow = wv * 16 + el;

        #pragma unroll
        for (int i = 0; i < 8; ++i) {
            const int k0 = i * 32 + q * 8;
            union { unsigned short us[8]; short8v v; } pk;
            if (ok) {
                const float* base = (k0 < D) ? (f + (size_t)ns * D + k0)
                                             : (f + (size_t)nd * D + (k0 - D));
                float4 v0 = *(const float4*)base;
                float4 v1 = *(const float4*)(base + 4);
                pk.us[0] = f2bf(v0.x); pk.us[1] = f2bf(v0.y);
                pk.us[2] = f2bf(v0.z); pk.us[3] = f2bf(v0.w);
                pk.us[4] = f2bf(v1.x); pk.us[5] = f2bf(v1.y);
                pk.us[6] = f2bf(v1.z); pk.us[7] = f2bf(v1.w);
            } else {
                #pragma unroll
                for (int j = 0; j < 8; ++j) pk.us[j] = 0;
            }
            *(short8v*)&msg_c[(i * EB + mrow) * 32 + q * 8] = pk.v;
        }
        {   // chunk 8: w feats, sqd, zero pad
            union { unsigned short us[8]; short8v v; } pk;
            #pragma unroll
            for (int j = 0; j < 8; ++j) pk.us[j] = 0;
            if (ok) {
                if (q < 2) {
                    float4 w0 = *(const float4*)(w + (size_t)ge * DE + q * 8);
                    float4 w1 = *(const float4*)(w + (size_t)ge * DE + q * 8 + 4);
                    pk.us[0] = f2bf(w0.x); pk.us[1] = f2bf(w0.y);
                    pk.us[2] = f2bf(w0.z); pk.us[3] = f2bf(w0.w);
                    pk.us[4] = f2bf(w1.x); pk.us[5] = f2bf(w1.y);
                    pk.us[6] = f2bf(w1.z); pk.us[7] = f2bf(w1.w);
                } else if (q == 2) {
                    float dx = x[ns*3+0] - x[nd*3+0];
                    float dy = x[ns*3+1] - x[nd*3+1];
                    float dz = x[ns*3+2] - x[nd*3+2];
                    pk.us[0] = f2bf(dx*dx + dy*dy + dz*dz);
                }
            }
            *(short8v*)&msg_c[(8 * EB + mrow) * 32 + q * 8] = pk.v;
        }
    }

    const int col = lane & 15;
    const int g   = lane >> 4;

    // prefetch layer-1 chunk-0 B-frags (independent of staging; done before barrier)
    const size_t wrow0 = (size_t)(wv * 32 + col) * KP1;
    const size_t wrow1 = (size_t)(wv * 32 + 16 + col) * KP1;
    short8v nb0 = *(const short8v*)&W1p[wrow0 + g * 8];
    short8v nb1 = *(const short8v*)&W1p[wrow1 + g * 8];

    __syncthreads();   // B0: msg staged block-wide

    // ---- layer 1: [64,288] x [288,32] per wave ----
    f32x4 acc[4][2];
    {
        float bv0 = bm1[wv * 32 + col];
        float bv1 = bm1[wv * 32 + 16 + col];
        #pragma unroll
        for (int rt = 0; rt < 4; ++rt) {
            acc[rt][0] = (f32x4){bv0, bv0, bv0, bv0};
            acc[rt][1] = (f32x4){bv1, bv1, bv1, bv1};
        }
    }
    #pragma unroll
    for (int c = 0; c < NCH1; ++c) {
        short8v b0 = nb0, b1 = nb1;
        if (c + 1 < NCH1) {
            nb0 = *(const short8v*)&W1p[wrow0 + (c + 1) * 32 + g * 8];
            nb1 = *(const short8v*)&W1p[wrow1 + (c + 1) * 32 + g * 8];
        }
        short8v a[4];
        #pragma unroll
        for (int rt = 0; rt < 4; ++rt)
            a[rt] = *(const short8v*)&msg_c[(c * EB + rt * 16 + col) * 32 + g * 8];
        #pragma unroll
        for (int rt = 0; rt < 4; ++rt) {
            acc[rt][0] = __builtin_amdgcn_mfma_f32_16x16x32_bf16(a[rt], b0, acc[rt][0], 0, 0, 0);
            acc[rt][1] = __builtin_amdgcn_mfma_f32_16x16x32_bf16(a[rt], b1, acc[rt][1], 0, 0, 0);
        }
    }
    __syncthreads();   // B1: all layer-1 LDS reads done -> chunks 0..3 reusable

    // hid (relu, bf16, pair-packed b32 writes) -> msg_c chunk wv (cols [wv*32,+32))
    const bool even = (col & 1) == 0;
    #pragma unroll
    for (int rt = 0; rt < 4; ++rt)
        #pragma unroll
        for (int j = 0; j < 2; ++j)
            #pragma unroll
            for (int r = 0; r < 4; ++r) {
                const int e = rt * 16 + g * 4 + r;
                float v  = fmaxf(acc[rt][j][r], 0.f);
                float vn = __shfl_xor(v, 1, 64);
                if (even) {
                    unsigned int pk = (unsigned)f2bf(v) | ((unsigned)f2bf(vn) << 16);
                    *(unsigned int*)&msg_c[(wv * EB + e) * 32 + j * 16 + col] = pk;
                }
            }
    __syncthreads();   // B2: hid complete block-wide

    // ---- layer 2: [64,128] x [128,32] per wave ----
    const size_t w2row0 = (size_t)(wv * 32 + col) * HD;
    const size_t w2row1 = (size_t)(wv * 32 + 16 + col) * HD;
    short8v m0 = *(const short8v*)&W2p[w2row0 + g * 8];
    short8v m1 = *(const short8v*)&W2p[w2row1 + g * 8];
    f32x4 acc2[4][2];
    {
        float bv0 = bm2[wv * 32 + col];
        float bv1 = bm2[wv * 32 + 16 + col];
        #pragma unroll
        for (int rt = 0; rt < 4; ++rt) {
            acc2[rt][0] = (f32x4){bv0, bv0, bv0, bv0};
            acc2[rt][1] = (f32x4){bv1, bv1, bv1, bv1};
        }
    }
    #pragma unroll
    for (int c = 0; c < NCH2; ++c) {
        short8v b0 = m0, b1 = m1;
        if (c + 1 < NCH2) {
            m0 = *(const short8v*)&W2p[w2row0 + (c + 1) * 32 + g * 8];
            m1 = *(const short8v*)&W2p[w2row1 + (c + 1) * 32 + g * 8];
        }
        short8v a[4];
        #pragma unroll
        for (int rt = 0; rt < 4; ++rt)
            a[rt] = *(const short8v*)&msg_c[(c * EB + rt * 16 + col) * 32 + g * 8];
        #pragma unroll
        for (int rt = 0; rt < 4; ++rt) {
            acc2[rt][0] = __builtin_amdgcn_mfma_f32_16x16x32_bf16(a[rt], b0, acc2[rt][0], 0, 0, 0);
            acc2[rt][1] = __builtin_amdgcn_mfma_f32_16x16x32_bf16(a[rt], b1, acc2[rt][1], 0, 0, 0);
        }
    }

    // ---- packed bf16 atomic scatter: even-col lanes issue (col, col+1) pairs ----
    #pragma unroll
    for (int rt = 0; rt < 4; ++rt)
        #pragma unroll
        for (int r = 0; r < 4; ++r) {
            const int e  = rt * 16 + g * 4 + r;
            const int ge = e0 + e;
            const int dg = s_dst[e];
            #pragma unroll
            for (int j = 0; j < 2; ++j) {
                float v  = acc2[rt][j][r];
                float vn = __shfl_xor(v, 1, 64);
                if (even && ge < E) {
                    unsigned int pk = (unsigned)f2bf(v) | ((unsigned)f2bf(vn) << 16);
                    ushort_t* p = msum + (size_t)dg * D + wv * 32 + j * 16 + col;
                    asm volatile("global_atomic_pk_add_bf16 %0, %1, off"
                                 :: "v"(p), "v"(pk) : "memory");
                }
            }
        }
}

// ---------------- edge kernel (fp32-atomic fallback, r3 structure) ----------------
__global__ __launch_bounds__(NT, 4) void edge_mfma_kernel_fa(
    const float* __restrict__ f, const float* __restrict__ x,
    const float* __restrict__ w, const int* __restrict__ src,
    const int* __restrict__ dst,
    const ushort_t* __restrict__ W1p, const float* __restrict__ bm1,
    const ushort_t* __restrict__ W2p, const float* __restrict__ bm2,
    float* msum, int E)
{
    __shared__ __align__(16) ushort_t msg_c[NCH1 * EB * 32];

    const int t    = threadIdx.x;
    const int lane = t & 63;
    const int wv   = t >> 6;
    const int e0   = blockIdx.x * EB;

    {
        const int el = lane >> 2;
        const int q  = lane & 3;
        const int ge = e0 + wv * 16 + el;
        const bool ok = ge < E;
        const int ns = ok ? src[ge] : 0;
        const int nd = ok ? dst[ge] : 0;
        const int mrow = wv * 16 + el;

        #pragma unroll
        for (int i = 0; i < 8; ++i) {
            const int k0 = i * 32 + q * 8;
            union { unsigned short us[8]; short8v v; } pk;
            if (ok) {
                const float* base = (k0 < D) ? (f + (size_t)ns * D + k0)
                                             : (f + (size_t)nd * D + (k0 - D));
                float4 v0 = *(const float4*)base;
                float4 v1 = *(const float4*)(base + 4);
                pk.us[0] = f2bf(v0.x); pk.us[1] = f2bf(v0.y);
                pk.us[2] = f2bf(v0.z); pk.us[3] = f2bf(v0.w);
                pk.us[4] = f2bf(v1.x); pk.us[5] = f2bf(v1.y);
                pk.us[6] = f2bf(v1.z); pk.us[7] = f2bf(v1.w);
            } else {
                #pragma unroll
                for (int j = 0; j < 8; ++j) pk.us[j] = 0;
            }
            *(short8v*)&msg_c[(i * EB + mrow) * 32 + q * 8] = pk.v;
        }
        {
            union { unsigned short us[8]; short8v v; } pk;
            #pragma unroll
            for (int j = 0; j < 8; ++j) pk.us[j] = 0;
            if (ok) {
                if (q < 2) {
                    float4 w0 = *(const float4*)(w + (size_t)ge * DE + q * 8);
                    float4 w1 = *(const float4*)(w + (size_t)ge * DE + q * 8 + 4);
                    pk.us[0] = f2bf(w0.x); pk.us[1] = f2bf(w0.y);
                    pk.us[2] = f2bf(w0.z); pk.us[3] = f2bf(w0.w);
                    pk.us[4] = f2bf(w1.x); pk.us[5] = f2bf(w1.y);
                    pk.us[6] = f2bf(w1.z); pk.us[7] = f2bf(w1.w);
                } else if (q == 2) {
                    float dx = x[ns*3+0] - x[nd*3+0];
                    float dy = x[ns*3+1] - x[nd*3+1];
                    float dz = x[ns*3+2] - x[nd*3+2];
                    pk.us[0] = f2bf(dx*dx + dy*dy + dz*dz);
                }
            }
            *(short8v*)&msg_c[(8 * EB + mrow) * 32 + q * 8] = pk.v;
        }
    }

    const int col  = lane & 15;
    const int g    = lane >> 4;
    const int erow = wv * 16 + col;

    f32x4 acc[8];
    #pragma unroll
    for (int ct = 0; ct < 8; ++ct) {
        float bv = bm1[ct * 16 + col];
        acc[ct] = (f32x4){bv, bv, bv, bv};
    }
    for (int c = 0; c < NCH1; ++c) {
        short8v a = *(const short8v*)&msg_c[(c * EB + erow) * 32 + g * 8];
        #pragma unroll
        for (int ct = 0; ct < 8; ++ct) {
            short8v b = *(const short8v*)&W1p[(size_t)(ct * 16 + col) * KP1 + c * 32 + g * 8];
            acc[ct] = __builtin_amdgcn_mfma_f32_16x16x32_bf16(a, b, acc[ct], 0, 0, 0);
        }
    }
    #pragma unroll
    for (int ct = 0; ct < 8; ++ct) {
        const int h  = ct * 16 + col;
        const int hc = h >> 5, hi = h & 31;
        #pragma unroll
        for (int r = 0; r < 4; ++r) {
            const int e = wv * 16 + g * 4 + r;
            msg_c[(hc * EB + e) * 32 + hi] = f2bf(fmaxf(acc[ct][r], 0.f));
        }
    }

    f32x4 acc2[8];
    #pragma unroll
    for (int ct = 0; ct < 8; ++ct) {
        float bv = bm2[ct * 16 + col];
        acc2[ct] = (f32x4){bv, bv, bv, bv};
    }
    for (int c = 0; c < NCH2; ++c) {
        short8v a = *(const short8v*)&msg_c[(c * EB + erow) * 32 + g * 8];
        #pragma unroll
        for (int ct = 0; ct < 8; ++ct) {
            short8v b = *(const short8v*)&W2p[(size_t)(ct * 16 + col) * HD + c * 32 + g * 8];
            acc2[ct] = __builtin_amdgcn_mfma_f32_16x16x32_bf16(a, b, acc2[ct], 0, 0, 0);
        }
    }

    #pragma unroll
    for (int r = 0; r < 4; ++r) {
        const int el = wv * 16 + g * 4 + r;
        const int ge = e0 + el;
        if (ge < E) {
            const int dg = dst[ge];
            float* p = msum + (size_t)dg * D + col;
            #pragma unroll
            for (int ct = 0; ct < 8; ++ct)
                atomicAdd(p + ct * 16, acc2[ct][r]);
        }
    }
}

// ---------------- fp32 full-fallback edge kernel ----------------
__global__ __launch_bounds__(NT, 2) void edge_kernel_f32(
    const float* __restrict__ f, const float* __restrict__ x,
    const float* __restrict__ w, const int* __restrict__ src,
    const int* __restrict__ dst,
    const float* __restrict__ Wm1, const float* __restrict__ bm1,
    const float* __restrict__ Wm2, const float* __restrict__ bm2,
    float* msum, int E)
{
    __shared__ __align__(16) float msg[32][MSG_PAD];
    __shared__ __align__(16) float hid[32][HID_PAD];
    __shared__ int s_src[32], s_dst[32];

    const int t  = threadIdx.x;
    const int e0 = blockIdx.x * 32;
    const int ne = min(32, E - e0);

    if (t < ne) { s_src[t] = src[e0 + t]; s_dst[t] = dst[e0 + t]; }
    __syncthreads();
    {
        const int half = t >> 7, tt = t & 127;
        for (int e = 0; e < ne; ++e) {
            int node = half ? s_dst[e] : s_src[e];
            msg[e][half * D + tt] = f[(size_t)node * D + tt];
        }
    }
    for (int idx = t; idx < 32 * DE; idx += NT) {
        int e = idx >> 4, k = idx & 15;
        if (e < ne) msg[e][2 * D + k] = w[(size_t)(e0 + e) * DE + k];
    }
    if (t < ne) {
        int s = s_src[t], dd = s_dst[t];
        float dx = x[s*3+0]-x[dd*3+0], dy = x[s*3+1]-x[dd*3+1], dz = x[s*3+2]-x[dd*3+2];
        msg[t][2*D + DE] = dx*dx + dy*dy + dz*dz;
    }
    __syncthreads();

    const int tc = t & 15, te2 = (t >> 4) * 2, c0 = tc * 8;
    float a1[2][8];
    #pragma unroll
    for (int c = 0; c < 8; ++c) { float bv = bm1[c0 + c]; a1[0][c] = bv; a1[1][c] = bv; }
    for (int i = 0; i < 272; i += 4) {
        float m0[4], m1[4];
        *(float4*)m0 = *(const float4*)&msg[te2][i];
        *(float4*)m1 = *(const float4*)&msg[te2 + 1][i];
        #pragma unroll
        for (int r = 0; r < 4; ++r) {
            float wr[8];
            *(float4*)&wr[0] = *(const float4*)(Wm1 + (size_t)(i + r) * HD + c0);
            *(float4*)&wr[4] = *(const float4*)(Wm1 + (size_t)(i + r) * HD + c0 + 4);
            #pragma unroll
            for (int c = 0; c < 8; ++c) { a1[0][c] += m0[r]*wr[c]; a1[1][c] += m1[r]*wr[c]; }
        }
    }
    {
        float m0 = msg[te2][272], m1 = msg[te2 + 1][272];
        float wr[8];
        *(float4*)&wr[0] = *(const float4*)(Wm1 + (size_t)272 * HD + c0);
        *(float4*)&wr[4] = *(const float4*)(Wm1 + (size_t)272 * HD + c0 + 4);
        #pragma unroll
        for (int c = 0; c < 8; ++c) { a1[0][c] += m0*wr[c]; a1[1][c] += m1*wr[c]; }
    }
    #pragma unroll
    for (int j = 0; j < 2; ++j) {
        float v[8];
        #pragma unroll
        for (int c = 0; c < 8; ++c) v[c] = fmaxf(a1[j][c], 0.f);
        *(float4*)&hid[te2 + j][c0] = *(float4*)&v[0];
        *(float4*)&hid[te2 + j][c0 + 4] = *(float4*)&v[4];
    }
    __syncthreads();
    float a2[2][8];
    #pragma unroll
    for (int c = 0; c < 8; ++c) { float bv = bm2[c0 + c]; a2[0][c] = bv; a2[1][c] = bv; }
    for (int h = 0; h < HD; h += 4) {
        float m0[4], m1[4];
        *(float4*)m0 = *(const float4*)&hid[te2][h];
        *(float4*)m1 = *(const float4*)&hid[te2 + 1][h];
        #pragma unroll
        for (int r = 0; r < 4; ++r) {
            float wr[8];
            *(float4*)&wr[0] = *(const float4*)(Wm2 + (size_t)(h + r) * D + c0);
            *(float4*)&wr[4] = *(const float4*)(Wm2 + (size_t)(h + r) * D + c0 + 4);
            #pragma unroll
            for (int c = 0; c < 8; ++c) { a2[0][c] += m0[r]*wr[c]; a2[1][c] += m1[r]*wr[c]; }
        }
    }
    #pragma unroll
    for (int j = 0; j < 2; ++j) {
        int e = te2 + j;
        if (e < ne) {
            float* p = msum + (size_t)s_dst[e] * D + c0;
            #pragma unroll
            for (int c = 0; c < 8; ++c) atomicAdd(p + c, a2[j][c]);
        }
    }
}

// ---------------- node kernel: update MLP (fp32 compute, templated msum dtype) ----------------
template<bool MB16>
__global__ __launch_bounds__(NT, 2) void node_kernel(
    const float* __restrict__ f, const void* __restrict__ msum_v,
    const float* __restrict__ Wu1, const float* __restrict__ bu1,
    const float* __restrict__ Wu2, const float* __restrict__ bu2,
    float* out, int Nn)
{
    __shared__ __align__(16) float hin[NB][HID_PAD];
    __shared__ __align__(16) float hid[NB][HID_PAD];
    const int t  = threadIdx.x;
    const int n0 = blockIdx.x * NB;
    const int nn = min(NB, Nn - n0);

    {
        const int half = t >> 7, tt = t & 127;
        for (int e = half; e < nn; e += 2) {
            size_t off = (size_t)(n0 + e) * D + tt;
            float mv = MB16 ? bf2f(((const ushort_t*)msum_v)[off])
                            : ((const float*)msum_v)[off];
            hin[e][tt] = mv + f[off];
        }
    }
    __syncthreads();

    const int tc = t & 15, te2 = (t >> 4) * 2, c0 = tc * 8;
    float a1[2][8];
    #pragma unroll
    for (int c = 0; c < 8; ++c) { float bv = bu1[c0 + c]; a1[0][c] = bv; a1[1][c] = bv; }
    for (int i = 0; i < D; i += 4) {
        float m0[4], m1[4];
        *(float4*)m0 = *(const float4*)&hin[te2][i];
        *(float4*)m1 = *(const float4*)&hin[te2 + 1][i];
        #pragma unroll
        for (int r = 0; r < 4; ++r) {
            float wr[8];
            *(float4*)&wr[0] = *(const float4*)(Wu1 + (size_t)(i + r) * HD + c0);
            *(float4*)&wr[4] = *(const float4*)(Wu1 + (size_t)(i + r) * HD + c0 + 4);
            #pragma unroll
            for (int c = 0; c < 8; ++c) { a1[0][c] += m0[r]*wr[c]; a1[1][c] += m1[r]*wr[c]; }
        }
    }
    #pragma unroll
    for (int j = 0; j < 2; ++j) {
        float v[8];
        #pragma unroll
        for (int c = 0; c < 8; ++c) v[c] = fmaxf(a1[j][c], 0.f);
        *(float4*)&hid[te2 + j][c0] = *(float4*)&v[0];
        *(float4*)&hid[te2 + j][c0 + 4] = *(float4*)&v[4];
    }
    __syncthreads();
    float a2[2][8];
    #pragma unroll
    for (int c = 0; c < 8; ++c) { float bv = bu2[c0 + c]; a2[0][c] = bv; a2[1][c] = bv; }
    for (int h = 0; h < HD; h += 4) {
        float m0[4], m1[4];
        *(float4*)m0 = *(const float4*)&hid[te2][h];
        *(float4*)m1 = *(const float4*)&hid[te2 + 1][h];
        #pragma unroll
        for (int r = 0; r < 4; ++r) {
            float wr[8];
            *(float4*)&wr[0] = *(const float4*)(Wu2 + (size_t)(h + r) * D + c0);
            *(float4*)&wr[4] = *(const float4*)(Wu2 + (size_t)(h + r) * D + c0 + 4);
            #pragma unroll
            for (int c = 0; c < 8; ++c) { a2[0][c] += m0[r]*wr[c]; a2[1][c] += m1[r]*wr[c]; }
        }
    }
    #pragma unroll
    for (int j = 0; j < 2; ++j) {
        int e = te2 + j, gn = n0 + e;
        if (e < nn) {
            *(float4*)(out + (size_t)gn * D + c0) = *(float4*)&a2[j][0];
            *(float4*)(out + (size_t)gn * D + c0 + 4) = *(float4*)&a2[j][4];
        }
    }
}

extern "C" void kernel_launch(void* const* d_in, const int* in_sizes, int n_in,
                              void* d_out, int out_size, void* d_ws, size_t ws_size,
                              hipStream_t stream) {
    const float* f   = (const float*)d_in[0];
    const float* x   = (const float*)d_in[1];
    const float* w   = (const float*)d_in[2];
    const int*   src = (const int*)d_in[3];
    const int*   dst = (const int*)d_in[4];
    const float* Wm1 = (const float*)d_in[5];
    const float* bm1 = (const float*)d_in[6];
    const float* Wm2 = (const float*)d_in[7];
    const float* bm2 = (const float*)d_in[8];
    const float* Wu1 = (const float*)d_in[9];
    const float* bu1 = (const float*)d_in[10];
    const float* Wu2 = (const float*)d_in[11];
    const float* bu2 = (const float*)d_in[12];

    const int Nn = in_sizes[0] / D;
    const int E  = in_sizes[3];

    const size_t wbytes = (size_t)(128 * KP1 + HD * D) * sizeof(ushort_t); // 106,496 B
    auto align512 = [](size_t v) { return (v + 511) & ~(size_t)511; };
    const size_t woff = align512(wbytes);

    const size_t msum_bf_bytes  = (size_t)Nn * D * 2;
    const size_t msum_f32_bytes = (size_t)Nn * D * 4;
    char* wsb = (char*)d_ws;

    if (ws_size >= woff + msum_bf_bytes) {
        // ---------------- primary: v5 edge kernel, bf16 msum ----------------
        ushort_t* W1p  = (ushort_t*)wsb;
        ushort_t* W2p  = W1p + 128 * KP1;
        ushort_t* msum = (ushort_t*)(wsb + woff);

        hipMemsetAsync(msum, 0, msum_bf_bytes, stream);
        const int rp_elems = 128 * KP1 + HD * D;
        repack_kernel<<<dim3((rp_elems + 255) / 256), dim3(256), 0, stream>>>(Wm1, Wm2, W1p, W2p);
        edge_mfma_kernel<<<dim3((E + EB - 1) / EB), dim3(NT), 0, stream>>>(
            f, x, w, src, dst, W1p, bm1, W2p, bm2, msum, E);
        node_kernel<true><<<dim3((Nn + NB - 1) / NB), dim3(NT), 0, stream>>>(
            f, msum, Wu1, bu1, Wu2, bu2, (float*)d_out, Nn);
        return;
    }

    // ---------------- fallbacks ----------------
    float* msum;
    ushort_t* W1p = nullptr;
    bool use_mfma;
    if (ws_size >= woff + msum_f32_bytes) {
        W1p = (ushort_t*)d_ws;
        msum = (float*)(wsb + woff);
        use_mfma = true;
    } else if (ws_size >= wbytes) {
        W1p = (ushort_t*)d_ws;
        msum = (float*)d_out;   // safe: node reads its own rows before writing, same dtype
        use_mfma = true;
    } else {
        use_mfma = false;
        msum = (ws_size >= msum_f32_bytes) ? (float*)d_ws : (float*)d_out;
    }

    hipMemsetAsync(msum, 0, msum_f32_bytes, stream);

    if (use_mfma) {
        ushort_t* W2p = W1p + 128 * KP1;
        const int rp_elems = 128 * KP1 + HD * D;
        repack_kernel<<<dim3((rp_elems + 255) / 256), dim3(256), 0, stream>>>(Wm1, Wm2, W1p, W2p);
        edge_mfma_kernel_fa<<<dim3((E + EB - 1) / EB), dim3(NT), 0, stream>>>(
            f, x, w, src, dst, W1p, bm1, W2p, bm2, msum, E);
    } else {
        edge_kernel_f32<<<dim3((E + 31) / 32), dim3(NT), 0, stream>>>(
            f, x, w, src, dst, Wm1, bm1, Wm2, bm2, msum, E);
    }
    node_kernel<false><<<dim3((Nn + NB - 1) / NB), dim3(NT), 0, stream>>>(
        f, msum, Wu1, bu1, Wu2, bu2, (float*)d_out, Nn);
}

// Round 6
// 514.066 us; speedup vs baseline: 2.9087x; 1.0485x over previous
//
#include <hip/hip_runtime.h>

#define D 128
#define HD 128
#define DE 16
#define MSG_IN 273
#define EB 64        // edges per block (mfma path)
#define NT 256
#define KP1 288      // padded msg K = 9 chunks of 32
#define NCH1 9
#define NCH2 4
#define NB 32
#define MSG_PAD 276  // fp32 fallback kernel
#define HID_PAD 132
#define CH8 (4 * EB * 64)   // ushort offset of chunk-8 region in lds[]

typedef __attribute__((ext_vector_type(8))) short short8v;
typedef __attribute__((ext_vector_type(4))) float f32x4;
typedef unsigned short ushort_t;

#define GLOAD_LDS16(gp, lp) \
    __builtin_amdgcn_global_load_lds((const __attribute__((address_space(1))) unsigned int*)(gp), \
                                     (__attribute__((address_space(3))) unsigned int*)(lp), 16, 0, 0)

__device__ __forceinline__ unsigned short f2bf(float v) {
    unsigned int u = __builtin_bit_cast(unsigned int, v);
    u += 0x7fffu + ((u >> 16) & 1u);
    return (unsigned short)(u >> 16);
}
__device__ __forceinline__ float bf2f(ushort_t u) {
    return __builtin_bit_cast(float, (unsigned int)u << 16);
}

// ---------------- weight repack: fp32 [K][N] -> bf16 transposed [N][Kpad] ----------------
__global__ void repack_kernel(const float* __restrict__ Wm1, const float* __restrict__ Wm2,
                              ushort_t* __restrict__ W1p, ushort_t* __restrict__ W2p) {
    int idx = blockIdx.x * 256 + threadIdx.x;
    const int n1 = 128 * KP1;
    if (idx < n1) {
        int n = idx / KP1, k = idx % KP1;
        float v = (k < MSG_IN) ? Wm1[(size_t)k * HD + n] : 0.f;
        W1p[idx] = f2bf(v);
    } else {
        int i2 = idx - n1;
        if (i2 < HD * D) {
            int n = i2 / HD, k = i2 % HD;
            W2p[i2] = f2bf(Wm2[(size_t)k * D + n]);
        }
    }
}

// ---------------- f -> bf16 pre-conversion ----------------
__global__ void fconv_kernel(const float* __restrict__ f, ushort_t* __restrict__ fb, int n8) {
    int i = blockIdx.x * 256 + threadIdx.x;
    if (i < n8) {
        float4 v0 = *(const float4*)(f + (size_t)i * 8);
        float4 v1 = *(const float4*)(f + (size_t)i * 8 + 4);
        union { ushort_t us[8]; short8v v; } pk;
        pk.us[0] = f2bf(v0.x); pk.us[1] = f2bf(v0.y);
        pk.us[2] = f2bf(v0.z); pk.us[3] = f2bf(v0.w);
        pk.us[4] = f2bf(v1.x); pk.us[5] = f2bf(v1.y);
        pk.us[6] = f2bf(v1.z); pk.us[7] = f2bf(v1.w);
        *(short8v*)(fb + (size_t)i * 8) = pk.v;
    }
}

// ---------------- edge kernel v6: gload_lds staging, swizzled 128B-row LDS ----------------
// LDS layout: pairs p=0..3 (k ranges [64p,64p+64)): [p][64 edges][64 k] bf16, 128B rows,
// granule swizzle s' = s ^ (row&7).  chunk 8 compact: [64][32 k], 2-bit swizzle.
// hid aliases pairs 0-1 after B1.
__global__ __launch_bounds__(NT, 4) void edge_mfma_kernel(
    const ushort_t* __restrict__ fbf, const float* __restrict__ x,
    const float* __restrict__ w, const int* __restrict__ src,
    const int* __restrict__ dst,
    const ushort_t* __restrict__ W1p, const float* __restrict__ bm1,
    const ushort_t* __restrict__ W2p, const float* __restrict__ bm2,
    ushort_t* msum, int E)
{
    __shared__ __align__(16) ushort_t lds[4 * EB * 64 + EB * 32];  // 36,864 B
    __shared__ int s_dst[EB];

    const int t    = threadIdx.x;
    const int lane = t & 63;
    const int wv   = t >> 6;
    const int e0   = blockIdx.x * EB;

    if (t < EB) s_dst[t] = (e0 + t < E) ? dst[e0 + t] : 0;

    // ---- f staging: 8 x global_load_lds_dwordx4, pre-swizzled global source ----
    {
        const int el8 = lane >> 3;          // row within 8-row window
        const int s   = lane & 7;           // physical granule = dest slot
        const int sl  = s ^ el8;            // logical granule (involution)
        const int geA = min(e0 + wv * 16 + el8,     E - 1);
        const int geB = min(e0 + wv * 16 + 8 + el8, E - 1);
        const int nsA = src[geA], ndA = dst[geA];
        const int nsB = src[geB], ndB = dst[geB];
        #pragma unroll
        for (int p = 0; p < 4; ++p) {
            const int n0 = (p < 2) ? nsA : ndA;
            const int n1 = (p < 2) ? nsB : ndB;
            const ushort_t* g0 = fbf + (size_t)n0 * D + (p & 1) * 64 + sl * 8;
            const ushort_t* g1 = fbf + (size_t)n1 * D + (p & 1) * 64 + sl * 8;
            GLOAD_LDS16(g0, &lds[(p * EB + wv * 16    ) * 64]);
            GLOAD_LDS16(g1, &lds[(p * EB + wv * 16 + 8) * 64]);
        }
    }
    // ---- chunk 8: w feats (k0..15), sqd (k16), zeros; 2-bit swizzle ----
    {
        const int el = lane >> 2, q = lane & 3;
        const int qp = q ^ (el & 3);
        const int ge = e0 + wv * 16 + el;
        const bool ok = ge < E;
        const int gc = min(ge, E - 1);
        union { ushort_t us[8]; short8v v; } pk;
        #pragma unroll
        for (int j = 0; j < 8; ++j) pk.us[j] = 0;
        if (ok) {
            if (q < 2) {
                float4 w0 = *(const float4*)(w + (size_t)gc * DE + q * 8);
                float4 w1 = *(const float4*)(w + (size_t)gc * DE + q * 8 + 4);
                pk.us[0] = f2bf(w0.x); pk.us[1] = f2bf(w0.y);
                pk.us[2] = f2bf(w0.z); pk.us[3] = f2bf(w0.w);
                pk.us[4] = f2bf(w1.x); pk.us[5] = f2bf(w1.y);
                pk.us[6] = f2bf(w1.z); pk.us[7] = f2bf(w1.w);
            } else if (q == 2) {
                const int ns = src[gc], nd = dst[gc];
                float dx = x[ns*3+0] - x[nd*3+0];
                float dy = x[ns*3+1] - x[nd*3+1];
                float dz = x[ns*3+2] - x[nd*3+2];
                pk.us[0] = f2bf(dx*dx + dy*dy + dz*dz);
            }
        }
        *(short8v*)&lds[CH8 + (wv * 16 + el) * 32 + qp * 8] = pk.v;
    }

    const int col = lane & 15;
    const int g   = lane >> 4;

    // prefetch layer-1 chunk-0 B-frags before the barrier
    const size_t wrow0 = (size_t)(wv * 32 + col) * KP1;
    const size_t wrow1 = (size_t)(wv * 32 + 16 + col) * KP1;
    short8v nb0 = *(const short8v*)&W1p[wrow0 + g * 8];
    short8v nb1 = *(const short8v*)&W1p[wrow1 + g * 8];

    __syncthreads();   // B0: staging complete (drains gload_lds + ds_writes)

    // ---- layer 1: [64,288] x [288,32] per wave ----
    f32x4 acc[4][2];
    {
        float bv0 = bm1[wv * 32 + col];
        float bv1 = bm1[wv * 32 + 16 + col];
        #pragma unroll
        for (int rt = 0; rt < 4; ++rt) {
            acc[rt][0] = (f32x4){bv0, bv0, bv0, bv0};
            acc[rt][1] = (f32x4){bv1, bv1, bv1, bv1};
        }
    }
    #pragma unroll
    for (int c = 0; c < NCH1; ++c) {
        short8v b0 = nb0, b1 = nb1;
        if (c + 1 < NCH1) {
            nb0 = *(const short8v*)&W1p[wrow0 + (c + 1) * 32 + g * 8];
            nb1 = *(const short8v*)&W1p[wrow1 + (c + 1) * 32 + g * 8];
        }
        short8v a[4];
        #pragma unroll
        for (int rt = 0; rt < 4; ++rt) {
            const int row = rt * 16 + col;
            if (c < 8) {
                const int sP = (((c & 1) << 2) + g) ^ (row & 7);
                a[rt] = *(const short8v*)&lds[((c >> 1) * EB + row) * 64 + sP * 8];
            } else {
                const int sP = g ^ (row & 3);
                a[rt] = *(const short8v*)&lds[CH8 + row * 32 + sP * 8];
            }
        }
        #pragma unroll
        for (int rt = 0; rt < 4; ++rt) {
            acc[rt][0] = __builtin_amdgcn_mfma_f32_16x16x32_bf16(a[rt], b0, acc[rt][0], 0, 0, 0);
            acc[rt][1] = __builtin_amdgcn_mfma_f32_16x16x32_bf16(a[rt], b1, acc[rt][1], 0, 0, 0);
        }
    }
    __syncthreads();   // B1: all layer-1 LDS reads done -> pairs 0-1 reusable

    // hid (relu, bf16, pair-packed b32) -> pairs 0-1 region, same swizzle
    const bool even = (col & 1) == 0;
    const int ph = wv >> 1;
    #pragma unroll
    for (int rt = 0; rt < 4; ++rt)
        #pragma unroll
        for (int j = 0; j < 2; ++j)
            #pragma unroll
            for (int r = 0; r < 4; ++r) {
                const int row = rt * 16 + g * 4 + r;
                float v  = fmaxf(acc[rt][j][r], 0.f);
                float vn = __shfl_xor(v, 1, 64);
                if (even) {
                    unsigned int pk2 = (unsigned)f2bf(v) | ((unsigned)f2bf(vn) << 16);
                    const int sH = (((wv & 1) << 2) + j * 2 + (col >> 3)) ^ (row & 7);
                    *(unsigned int*)&lds[(ph * EB + row) * 64 + sH * 8 + (col & 7)] = pk2;
                }
            }
    __syncthreads();   // B2: hid complete block-wide

    // ---- layer 2: [64,128] x [128,32] per wave ----
    const size_t w2r0 = (size_t)(wv * 32 + col) * HD;
    const size_t w2r1 = (size_t)(wv * 32 + 16 + col) * HD;
    short8v m0 = *(const short8v*)&W2p[w2r0 + g * 8];
    short8v m1 = *(const short8v*)&W2p[w2r1 + g * 8];
    f32x4 acc2[4][2];
    {
        float bv0 = bm2[wv * 32 + col];
        float bv1 = bm2[wv * 32 + 16 + col];
        #pragma unroll
        for (int rt = 0; rt < 4; ++rt) {
            acc2[rt][0] = (f32x4){bv0, bv0, bv0, bv0};
            acc2[rt][1] = (f32x4){bv1, bv1, bv1, bv1};
        }
    }
    #pragma unroll
    for (int c = 0; c < NCH2; ++c) {
        short8v b0 = m0, b1 = m1;
        if (c + 1 < NCH2) {
            m0 = *(const short8v*)&W2p[w2r0 + (c + 1) * 32 + g * 8];
            m1 = *(const short8v*)&W2p[w2r1 + (c + 1) * 32 + g * 8];
        }
        short8v a[4];
        #pragma unroll
        for (int rt = 0; rt < 4; ++rt) {
            const int row = rt * 16 + col;
            const int sP = (((c & 1) << 2) + g) ^ (row & 7);
            a[rt] = *(const short8v*)&lds[((c >> 1) * EB + row) * 64 + sP * 8];
        }
        #pragma unroll
        for (int rt = 0; rt < 4; ++rt) {
            acc2[rt][0] = __builtin_amdgcn_mfma_f32_16x16x32_bf16(a[rt], b0, acc2[rt][0], 0, 0, 0);
            acc2[rt][1] = __builtin_amdgcn_mfma_f32_16x16x32_bf16(a[rt], b1, acc2[rt][1], 0, 0, 0);
        }
    }

    // ---- packed bf16 atomic scatter ----
    #pragma unroll
    for (int rt = 0; rt < 4; ++rt)
        #pragma unroll
        for (int r = 0; r < 4; ++r) {
            const int e  = rt * 16 + g * 4 + r;
            const int ge = e0 + e;
            const int dg = s_dst[e];
            #pragma unroll
            for (int j = 0; j < 2; ++j) {
                float v  = acc2[rt][j][r];
                float vn = __shfl_xor(v, 1, 64);
                if (even && ge < E) {
                    unsigned int pk2 = (unsigned)f2bf(v) | ((unsigned)f2bf(vn) << 16);
                    ushort_t* p = msum + (size_t)dg * D + wv * 32 + j * 16 + col;
                    asm volatile("global_atomic_pk_add_bf16 %0, %1, off"
                                 :: "v"(p), "v"(pk2) : "memory");
                }
            }
        }
}

// ---------------- edge kernel (fp32-atomic fallback, r3 structure, fp32 f) ----------------
__global__ __launch_bounds__(NT, 4) void edge_mfma_kernel_fa(
    const float* __restrict__ f, const float* __restrict__ x,
    const float* __restrict__ w, const int* __restrict__ src,
    const int* __restrict__ dst,
    const ushort_t* __restrict__ W1p, const float* __restrict__ bm1,
    const ushort_t* __restrict__ W2p, const float* __restrict__ bm2,
    float* msum, int E)
{
    __shared__ __align__(16) ushort_t msg_c[NCH1 * EB * 32];

    const int t    = threadIdx.x;
    const int lane = t & 63;
    const int wv   = t >> 6;
    const int e0   = blockIdx.x * EB;

    {
        const int el = lane >> 2;
        const int q  = lane & 3;
        const int ge = e0 + wv * 16 + el;
        const bool ok = ge < E;
        const int ns = ok ? src[ge] : 0;
        const int nd = ok ? dst[ge] : 0;
        const int mrow = wv * 16 + el;

        #pragma unroll
        for (int i = 0; i < 8; ++i) {
            const int k0 = i * 32 + q * 8;
            union { unsigned short us[8]; short8v v; } pk;
            if (ok) {
                const float* base = (k0 < D) ? (f + (size_t)ns * D + k0)
                                             : (f + (size_t)nd * D + (k0 - D));
                float4 v0 = *(const float4*)base;
                float4 v1 = *(const float4*)(base + 4);
                pk.us[0] = f2bf(v0.x); pk.us[1] = f2bf(v0.y);
                pk.us[2] = f2bf(v0.z); pk.us[3] = f2bf(v0.w);
                pk.us[4] = f2bf(v1.x); pk.us[5] = f2bf(v1.y);
                pk.us[6] = f2bf(v1.z); pk.us[7] = f2bf(v1.w);
            } else {
                #pragma unroll
                for (int j = 0; j < 8; ++j) pk.us[j] = 0;
            }
            *(short8v*)&msg_c[(i * EB + mrow) * 32 + q * 8] = pk.v;
        }
        {
            union { unsigned short us[8]; short8v v; } pk;
            #pragma unroll
            for (int j = 0; j < 8; ++j) pk.us[j] = 0;
            if (ok) {
                if (q < 2) {
                    float4 w0 = *(const float4*)(w + (size_t)ge * DE + q * 8);
                    float4 w1 = *(const float4*)(w + (size_t)ge * DE + q * 8 + 4);
                    pk.us[0] = f2bf(w0.x); pk.us[1] = f2bf(w0.y);
                    pk.us[2] = f2bf(w0.z); pk.us[3] = f2bf(w0.w);
                    pk.us[4] = f2bf(w1.x); pk.us[5] = f2bf(w1.y);
                    pk.us[6] = f2bf(w1.z); pk.us[7] = f2bf(w1.w);
                } else if (q == 2) {
                    float dx = x[ns*3+0] - x[nd*3+0];
                    float dy = x[ns*3+1] - x[nd*3+1];
                    float dz = x[ns*3+2] - x[nd*3+2];
                    pk.us[0] = f2bf(dx*dx + dy*dy + dz*dz);
                }
            }
            *(short8v*)&msg_c[(8 * EB + mrow) * 32 + q * 8] = pk.v;
        }
    }

    const int col  = lane & 15;
    const int g    = lane >> 4;
    const int erow = wv * 16 + col;

    f32x4 acc[8];
    #pragma unroll
    for (int ct = 0; ct < 8; ++ct) {
        float bv = bm1[ct * 16 + col];
        acc[ct] = (f32x4){bv, bv, bv, bv};
    }
    for (int c = 0; c < NCH1; ++c) {
        short8v a = *(const short8v*)&msg_c[(c * EB + erow) * 32 + g * 8];
        #pragma unroll
        for (int ct = 0; ct < 8; ++ct) {
            short8v b = *(const short8v*)&W1p[(size_t)(ct * 16 + col) * KP1 + c * 32 + g * 8];
            acc[ct] = __builtin_amdgcn_mfma_f32_16x16x32_bf16(a, b, acc[ct], 0, 0, 0);
        }
    }
    #pragma unroll
    for (int ct = 0; ct < 8; ++ct) {
        const int h  = ct * 16 + col;
        const int hc = h >> 5, hi = h & 31;
        #pragma unroll
        for (int r = 0; r < 4; ++r) {
            const int e = wv * 16 + g * 4 + r;
            msg_c[(hc * EB + e) * 32 + hi] = f2bf(fmaxf(acc[ct][r], 0.f));
        }
    }

    f32x4 acc2[8];
    #pragma unroll
    for (int ct = 0; ct < 8; ++ct) {
        float bv = bm2[ct * 16 + col];
        acc2[ct] = (f32x4){bv, bv, bv, bv};
    }
    for (int c = 0; c < NCH2; ++c) {
        short8v a = *(const short8v*)&msg_c[(c * EB + erow) * 32 + g * 8];
        #pragma unroll
        for (int ct = 0; ct < 8; ++ct) {
            short8v b = *(const short8v*)&W2p[(size_t)(ct * 16 + col) * HD + c * 32 + g * 8];
            acc2[ct] = __builtin_amdgcn_mfma_f32_16x16x32_bf16(a, b, acc2[ct], 0, 0, 0);
        }
    }

    #pragma unroll
    for (int r = 0; r < 4; ++r) {
        const int el = wv * 16 + g * 4 + r;
        const int ge = e0 + el;
        if (ge < E) {
            const int dg = dst[ge];
            float* p = msum + (size_t)dg * D + col;
            #pragma unroll
            for (int ct = 0; ct < 8; ++ct)
                atomicAdd(p + ct * 16, acc2[ct][r]);
        }
    }
}

// ---------------- fp32 full-fallback edge kernel ----------------
__global__ __launch_bounds__(NT, 2) void edge_kernel_f32(
    const float* __restrict__ f, const float* __restrict__ x,
    const float* __restrict__ w, const int* __restrict__ src,
    const int* __restrict__ dst,
    const float* __restrict__ Wm1, const float* __restrict__ bm1,
    const float* __restrict__ Wm2, const float* __restrict__ bm2,
    float* msum, int E)
{
    __shared__ __align__(16) float msg[32][MSG_PAD];
    __shared__ __align__(16) float hid[32][HID_PAD];
    __shared__ int s_src[32], s_dst[32];

    const int t  = threadIdx.x;
    const int e0 = blockIdx.x * 32;
    const int ne = min(32, E - e0);

    if (t < ne) { s_src[t] = src[e0 + t]; s_dst[t] = dst[e0 + t]; }
    __syncthreads();
    {
        const int half = t >> 7, tt = t & 127;
        for (int e = 0; e < ne; ++e) {
            int node = half ? s_dst[e] : s_src[e];
            msg[e][half * D + tt] = f[(size_t)node * D + tt];
        }
    }
    for (int idx = t; idx < 32 * DE; idx += NT) {
        int e = idx >> 4, k = idx & 15;
        if (e < ne) msg[e][2 * D + k] = w[(size_t)(e0 + e) * DE + k];
    }
    if (t < ne) {
        int s = s_src[t], dd = s_dst[t];
        float dx = x[s*3+0]-x[dd*3+0], dy = x[s*3+1]-x[dd*3+1], dz = x[s*3+2]-x[dd*3+2];
        msg[t][2*D + DE] = dx*dx + dy*dy + dz*dz;
    }
    __syncthreads();

    const int tc = t & 15, te2 = (t >> 4) * 2, c0 = tc * 8;
    float a1[2][8];
    #pragma unroll
    for (int c = 0; c < 8; ++c) { float bv = bm1[c0 + c]; a1[0][c] = bv; a1[1][c] = bv; }
    for (int i = 0; i < 272; i += 4) {
        float m0[4], m1[4];
        *(float4*)m0 = *(const float4*)&msg[te2][i];
        *(float4*)m1 = *(const float4*)&msg[te2 + 1][i];
        #pragma unroll
        for (int r = 0; r < 4; ++r) {
            float wr[8];
            *(float4*)&wr[0] = *(const float4*)(Wm1 + (size_t)(i + r) * HD + c0);
            *(float4*)&wr[4] = *(const float4*)(Wm1 + (size_t)(i + r) * HD + c0 + 4);
            #pragma unroll
            for (int c = 0; c < 8; ++c) { a1[0][c] += m0[r]*wr[c]; a1[1][c] += m1[r]*wr[c]; }
        }
    }
    {
        float m0 = msg[te2][272], m1 = msg[te2 + 1][272];
        float wr[8];
        *(float4*)&wr[0] = *(const float4*)(Wm1 + (size_t)272 * HD + c0);
        *(float4*)&wr[4] = *(const float4*)(Wm1 + (size_t)272 * HD + c0 + 4);
        #pragma unroll
        for (int c = 0; c < 8; ++c) { a1[0][c] += m0*wr[c]; a1[1][c] += m1*wr[c]; }
    }
    #pragma unroll
    for (int j = 0; j < 2; ++j) {
        float v[8];
        #pragma unroll
        for (int c = 0; c < 8; ++c) v[c] = fmaxf(a1[j][c], 0.f);
        *(float4*)&hid[te2 + j][c0] = *(float4*)&v[0];
        *(float4*)&hid[te2 + j][c0 + 4] = *(float4*)&v[4];
    }
    __syncthreads();
    float a2[2][8];
    #pragma unroll
    for (int c = 0; c < 8; ++c) { float bv = bm2[c0 + c]; a2[0][c] = bv; a2[1][c] = bv; }
    for (int h = 0; h < HD; h += 4) {
        float m0[4], m1[4];
        *(float4*)m0 = *(const float4*)&hid[te2][h];
        *(float4*)m1 = *(const float4*)&hid[te2 + 1][h];
        #pragma unroll
        for (int r = 0; r < 4; ++r) {
            float wr[8];
            *(float4*)&wr[0] = *(const float4*)(Wm2 + (size_t)(h + r) * D + c0);
            *(float4*)&wr[4] = *(const float4*)(Wm2 + (size_t)(h + r) * D + c0 + 4);
            #pragma unroll
            for (int c = 0; c < 8; ++c) { a2[0][c] += m0[r]*wr[c]; a2[1][c] += m1[r]*wr[c]; }
        }
    }
    #pragma unroll
    for (int j = 0; j < 2; ++j) {
        int e = te2 + j;
        if (e < ne) {
            float* p = msum + (size_t)s_dst[e] * D + c0;
            #pragma unroll
            for (int c = 0; c < 8; ++c) atomicAdd(p + c, a2[j][c]);
        }
    }
}

// ---------------- node kernel: update MLP (fp32 compute, templated msum dtype) ----------------
template<bool MB16>
__global__ __launch_bounds__(NT, 2) void node_kernel(
    const float* __restrict__ f, const void* __restrict__ msum_v,
    const float* __restrict__ Wu1, const float* __restrict__ bu1,
    const float* __restrict__ Wu2, const float* __restrict__ bu2,
    float* out, int Nn)
{
    __shared__ __align__(16) float hin[NB][HID_PAD];
    __shared__ __align__(16) float hid[NB][HID_PAD];
    const int t  = threadIdx.x;
    const int n0 = blockIdx.x * NB;
    const int nn = min(NB, Nn - n0);

    {
        const int half = t >> 7, tt = t & 127;
        for (int e = half; e < nn; e += 2) {
            size_t off = (size_t)(n0 + e) * D + tt;
            float mv = MB16 ? bf2f(((const ushort_t*)msum_v)[off])
                            : ((const float*)msum_v)[off];
            hin[e][tt] = mv + f[off];
        }
    }
    __syncthreads();

    const int tc = t & 15, te2 = (t >> 4) * 2, c0 = tc * 8;
    float a1[2][8];
    #pragma unroll
    for (int c = 0; c < 8; ++c) { float bv = bu1[c0 + c]; a1[0][c] = bv; a1[1][c] = bv; }
    for (int i = 0; i < D; i += 4) {
        float m0[4], m1[4];
        *(float4*)m0 = *(const float4*)&hin[te2][i];
        *(float4*)m1 = *(const float4*)&hin[te2 + 1][i];
        #pragma unroll
        for (int r = 0; r < 4; ++r) {
            float wr[8];
            *(float4*)&wr[0] = *(const float4*)(Wu1 + (size_t)(i + r) * HD + c0);
            *(float4*)&wr[4] = *(const float4*)(Wu1 + (size_t)(i + r) * HD + c0 + 4);
            #pragma unroll
            for (int c = 0; c < 8; ++c) { a1[0][c] += m0[r]*wr[c]; a1[1][c] += m1[r]*wr[c]; }
        }
    }
    #pragma unroll
    for (int j = 0; j < 2; ++j) {
        float v[8];
        #pragma unroll
        for (int c = 0; c < 8; ++c) v[c] = fmaxf(a1[j][c], 0.f);
        *(float4*)&hid[te2 + j][c0] = *(float4*)&v[0];
        *(float4*)&hid[te2 + j][c0 + 4] = *(float4*)&v[4];
    }
    __syncthreads();
    float a2[2][8];
    #pragma unroll
    for (int c = 0; c < 8; ++c) { float bv = bu2[c0 + c]; a2[0][c] = bv; a2[1][c] = bv; }
    for (int h = 0; h < HD; h += 4) {
        float m0[4], m1[4];
        *(float4*)m0 = *(const float4*)&hid[te2][h];
        *(float4*)m1 = *(const float4*)&hid[te2 + 1][h];
        #pragma unroll
        for (int r = 0; r < 4; ++r) {
            float wr[8];
            *(float4*)&wr[0] = *(const float4*)(Wu2 + (size_t)(h + r) * D + c0);
            *(float4*)&wr[4] = *(const float4*)(Wu2 + (size_t)(h + r) * D + c0 + 4);
            #pragma unroll
            for (int c = 0; c < 8; ++c) { a2[0][c] += m0[r]*wr[c]; a2[1][c] += m1[r]*wr[c]; }
        }
    }
    #pragma unroll
    for (int j = 0; j < 2; ++j) {
        int e = te2 + j, gn = n0 + e;
        if (e < nn) {
            *(float4*)(out + (size_t)gn * D + c0) = *(float4*)&a2[j][0];
            *(float4*)(out + (size_t)gn * D + c0 + 4) = *(float4*)&a2[j][4];
        }
    }
}

extern "C" void kernel_launch(void* const* d_in, const int* in_sizes, int n_in,
                              void* d_out, int out_size, void* d_ws, size_t ws_size,
                              hipStream_t stream) {
    const float* f   = (const float*)d_in[0];
    const float* x   = (const float*)d_in[1];
    const float* w   = (const float*)d_in[2];
    const int*   src = (const int*)d_in[3];
    const int*   dst = (const int*)d_in[4];
    const float* Wm1 = (const float*)d_in[5];
    const float* bm1 = (const float*)d_in[6];
    const float* Wm2 = (const float*)d_in[7];
    const float* bm2 = (const float*)d_in[8];
    const float* Wu1 = (const float*)d_in[9];
    const float* bu1 = (const float*)d_in[10];
    const float* Wu2 = (const float*)d_in[11];
    const float* bu2 = (const float*)d_in[12];

    const int Nn = in_sizes[0] / D;
    const int E  = in_sizes[3];

    const size_t wbytes = (size_t)(128 * KP1 + HD * D) * sizeof(ushort_t); // 106,496 B
    auto align512 = [](size_t v) { return (v + 511) & ~(size_t)511; };

    const size_t fb_bytes      = (size_t)Nn * D * 2;
    const size_t msum_bf_bytes = (size_t)Nn * D * 2;
    const size_t msum_f32_bytes= (size_t)Nn * D * 4;
    char* wsb = (char*)d_ws;

    // primary layout: [W1p|W2p][fbf][msum_bf16]
    size_t off = 0;
    const size_t o_w  = off; off = align512(off + wbytes);
    const size_t o_fb = off; off = align512(off + fb_bytes);
    const size_t o_ms = off; off = align512(off + msum_bf_bytes);
    const size_t primary_total = off;

    if (ws_size >= primary_total) {
        ushort_t* W1p  = (ushort_t*)(wsb + o_w);
        ushort_t* W2p  = W1p + 128 * KP1;
        ushort_t* fbf  = (ushort_t*)(wsb + o_fb);
        ushort_t* msum = (ushort_t*)(wsb + o_ms);

        hipMemsetAsync(msum, 0, msum_bf_bytes, stream);
        const int rp_elems = 128 * KP1 + HD * D;
        repack_kernel<<<dim3((rp_elems + 255) / 256), dim3(256), 0, stream>>>(Wm1, Wm2, W1p, W2p);
        const int n8 = Nn * D / 8;
        fconv_kernel<<<dim3((n8 + 255) / 256), dim3(256), 0, stream>>>(f, fbf, n8);
        edge_mfma_kernel<<<dim3((E + EB - 1) / EB), dim3(NT), 0, stream>>>(
            fbf, x, w, src, dst, W1p, bm1, W2p, bm2, msum, E);
        node_kernel<true><<<dim3((Nn + NB - 1) / NB), dim3(NT), 0, stream>>>(
            f, msum, Wu1, bu1, Wu2, bu2, (float*)d_out, Nn);
        return;
    }

    // ---------------- fallbacks ----------------
    const size_t woff = align512(wbytes);
    float* msum;
    ushort_t* W1p = nullptr;
    bool use_mfma;
    if (ws_size >= woff + msum_f32_bytes) {
        W1p = (ushort_t*)d_ws;
        msum = (float*)(wsb + woff);
        use_mfma = true;
    } else if (ws_size >= wbytes) {
        W1p = (ushort_t*)d_ws;
        msum = (float*)d_out;   // safe: node reads its own rows before writing
        use_mfma = true;
    } else {
        use_mfma = false;
        msum = (ws_size >= msum_f32_bytes) ? (float*)d_ws : (float*)d_out;
    }

    hipMemsetAsync(msum, 0, msum_f32_bytes, stream);

    if (use_mfma) {
        ushort_t* W2p = W1p + 128 * KP1;
        const int rp_elems = 128 * KP1 + HD * D;
        repack_kernel<<<dim3((rp_elems + 255) / 256), dim3(256), 0, stream>>>(Wm1, Wm2, W1p, W2p);
        edge_mfma_kernel_fa<<<dim3((E + EB - 1) / EB), dim3(NT), 0, stream>>>(
            f, x, w, src, dst, W1p, bm1, W2p, bm2, msum, E);
    } else {
        edge_kernel_f32<<<dim3((E + 31) / 32), dim3(NT), 0, stream>>>(
            f, x, w, src, dst, Wm1, bm1, Wm2, bm2, msum, E);
    }
    node_kernel<false><<<dim3((Nn + NB - 1) / NB), dim3(NT), 0, stream>>>(
        f, msum, Wu1, bu1, Wu2, bu2, (float*)d_out, Nn);
}